// Round 1
// baseline (743.769 us; speedup 1.0000x reference)
//
#include <hip/hip_runtime.h>
#include <hip/hip_bf16.h>

// GraphSAGE encoder: 2x (mean-aggregate + dense) + output GEMM.
// Strategy: build CSR (dst -> list of src) once per launch, then
// aggregation = per-node gather-reduce (no float atomics).

#define N_NODES 50000

// ---------------- CSR build ----------------

__global__ void k_count(const int* __restrict__ dst, int* __restrict__ deg, int E) {
    int e = blockIdx.x * blockDim.x + threadIdx.x;
    if (e < E) atomicAdd(&deg[dst[e]], 1);
}

// Single-block exclusive scan: deg[0..n) -> off[0..n], cur = off copy.
__global__ void k_scan(const int* __restrict__ deg, int* __restrict__ off,
                       int* __restrict__ cur, int n) {
    __shared__ int s[1024];
    int tid = threadIdx.x;
    int chunk = (n + 1023) / 1024;
    int beg = tid * chunk;
    int end = beg + chunk; if (end > n) end = n;
    int sum = 0;
    for (int i = beg; i < end; ++i) sum += deg[i];
    s[tid] = sum;
    __syncthreads();
    for (int ofs = 1; ofs < 1024; ofs <<= 1) {
        int t = (tid >= ofs) ? s[tid - ofs] : 0;
        __syncthreads();
        s[tid] += t;
        __syncthreads();
    }
    int run = s[tid] - sum;   // exclusive prefix of this thread's chunk
    for (int i = beg; i < end; ++i) {
        off[i] = run; cur[i] = run; run += deg[i];
    }
    if (tid == 1023) off[n] = s[1023];
}

__global__ void k_fill(const int* __restrict__ src, const int* __restrict__ dst,
                       int* __restrict__ cur, int* __restrict__ col, int E) {
    int e = blockIdx.x * blockDim.x + threadIdx.x;
    if (e < E) {
        int d = dst[e];
        int p = atomicAdd(&cur[d], 1);
        col[p] = src[e];
    }
}

// ---------------- mean aggregation (one wave per node) ----------------

template <int DIN>
__global__ __launch_bounds__(256) void k_agg(const float* __restrict__ feat,
                                             const int* __restrict__ off,
                                             const int* __restrict__ col,
                                             float* __restrict__ agg, int n) {
    int wave = (int)((blockIdx.x * (unsigned)blockDim.x + threadIdx.x) >> 6);
    int lane = threadIdx.x & 63;
    if (wave >= n) return;
    int s0 = off[wave], s1 = off[wave + 1];
    float a0 = 0.f, a1 = 0.f;
    int e = s0;
    // unroll by 4 to keep 4 independent gathers in flight
    for (; e + 4 <= s1; e += 4) {
        int sA = col[e], sB = col[e + 1], sC = col[e + 2], sD = col[e + 3];
        const float* rA = feat + (size_t)sA * DIN;
        const float* rB = feat + (size_t)sB * DIN;
        const float* rC = feat + (size_t)sC * DIN;
        const float* rD = feat + (size_t)sD * DIN;
        a0 += rA[lane]; a0 += rB[lane]; a0 += rC[lane]; a0 += rD[lane];
        if (DIN == 128) {
            a1 += rA[lane + 64]; a1 += rB[lane + 64];
            a1 += rC[lane + 64]; a1 += rD[lane + 64];
        }
    }
    for (; e < s1; ++e) {
        const float* r = feat + (size_t)col[e] * DIN;
        a0 += r[lane];
        if (DIN == 128) a1 += r[lane + 64];
    }
    float inv = 1.f / fmaxf((float)(s1 - s0), 1.f);
    agg[(size_t)wave * DIN + lane] = a0 * inv;
    if (DIN == 128) agg[(size_t)wave * DIN + lane + 64] = a1 * inv;
}

// ---------------- fused dense: out = act(A@Wl + [X@Wr] + b) ----------------
// 8 nodes per block staged in LDS; in-place out==A is safe (full rows staged
// before any write, and rows are block-exclusive).

template <int DIN, int DOUT, bool RELU, bool HAS_R>
__global__ __launch_bounds__(256) void k_dense(const float* __restrict__ A,
                                               const float* __restrict__ X,
                                               const float* __restrict__ Wl,
                                               const float* __restrict__ Wr,
                                               const float* __restrict__ b,
                                               float* __restrict__ out, int n) {
    constexpr int NODES = 8;
    __shared__ float sA[NODES][DIN];
    __shared__ float sX[HAS_R ? NODES : 1][HAS_R ? DIN : 1];
    int nb = blockIdx.x * NODES;
    for (int t = threadIdx.x; t < NODES * DIN; t += blockDim.x) {
        int nn = t / DIN, i = t % DIN;
        int node = nb + nn;
        sA[nn][i] = (node < n) ? A[(size_t)node * DIN + i] : 0.f;
        if (HAS_R) sX[nn][i] = (node < n) ? X[(size_t)node * DIN + i] : 0.f;
    }
    __syncthreads();

    constexpr int GROUPS = 256 / DOUT;     // 2 (DOUT=128) or 4 (DOUT=64)
    constexpr int NPG = NODES / GROUPS;    // 4 or 2
    int j = threadIdx.x % DOUT;
    int g = threadIdx.x / DOUT;
    float acc[NPG];
    float bj = b[j];
#pragma unroll
    for (int nn = 0; nn < NPG; ++nn) acc[nn] = bj;

#pragma unroll 8
    for (int i = 0; i < DIN; ++i) {
        float wl = Wl[i * DOUT + j];
        float wr = HAS_R ? Wr[i * DOUT + j] : 0.f;
#pragma unroll
        for (int nn = 0; nn < NPG; ++nn) {
            int node = g * NPG + nn;
            acc[nn] += sA[node][i] * wl;
            if (HAS_R) acc[nn] += sX[node][i] * wr;
        }
    }
#pragma unroll
    for (int nn = 0; nn < NPG; ++nn) {
        int node = nb + g * NPG + nn;
        if (node < n) {
            float v = acc[nn];
            if (RELU) v = fmaxf(v, 0.f);
            out[(size_t)node * DOUT + j] = v;
        }
    }
}

// ---------------- launch ----------------

static inline size_t align256(size_t x) { return (x + 255) & ~(size_t)255; }

extern "C" void kernel_launch(void* const* d_in, const int* in_sizes, int n_in,
                              void* d_out, int out_size, void* d_ws, size_t ws_size,
                              hipStream_t stream) {
    const float* x   = (const float*)d_in[0];
    const int*   ei  = (const int*)d_in[1];
    const float* Wl1 = (const float*)d_in[2];
    const float* bl1 = (const float*)d_in[3];
    const float* Wr1 = (const float*)d_in[4];
    const float* Wl2 = (const float*)d_in[5];
    const float* bl2 = (const float*)d_in[6];
    const float* Wr2 = (const float*)d_in[7];
    const float* Wo  = (const float*)d_in[8];
    const float* bo  = (const float*)d_in[9];

    const int N = in_sizes[0] / 64;        // 50000
    const int E = in_sizes[1] / 2;         // 1600000
    const int* src = ei;
    const int* dst = ei + E;

    // workspace carve
    char* ws = (char*)d_ws;
    int* deg = (int*)ws;            ws += align256((size_t)N * 4);
    int* off = (int*)ws;            ws += align256((size_t)(N + 1) * 4);
    int* cur = (int*)ws;            ws += align256((size_t)N * 4);
    int* col = (int*)ws;            ws += align256((size_t)E * 4);
    float* B1 = (float*)ws;         ws += align256((size_t)N * 128 * 4); // agg1/agg2/h2
    float* B2 = (float*)ws;         ws += align256((size_t)N * 128 * 4); // h1

    // 1. CSR build
    hipMemsetAsync(deg, 0, (size_t)N * 4, stream);
    int ebl = (E + 255) / 256;
    k_count<<<ebl, 256, 0, stream>>>(dst, deg, E);
    k_scan<<<1, 1024, 0, stream>>>(deg, off, cur, N);
    k_fill<<<ebl, 256, 0, stream>>>(src, dst, cur, col, E);

    // 2. layer 1
    int aggbl1 = (N * 64 + 255) / 256;     // one wave per node
    k_agg<64><<<aggbl1, 256, 0, stream>>>(x, off, col, B1, N);
    int dbl = (N + 7) / 8;
    k_dense<64, 128, true, true><<<dbl, 256, 0, stream>>>(B1, x, Wl1, Wr1, bl1, B2, N);

    // 3. layer 2 (h2 written in-place over agg2 in B1)
    int aggbl2 = (N * 64 + 255) / 256;
    k_agg<128><<<aggbl2, 256, 0, stream>>>(B2, off, col, B1, N);
    k_dense<128, 128, true, true><<<dbl, 256, 0, stream>>>(B1, B2, Wl2, Wr2, bl2, B1, N);

    // 4. output GEMM (no relu, no right term)
    k_dense<128, 64, false, false><<<dbl, 256, 0, stream>>>(B1, nullptr, Wo, nullptr, bo,
                                                            (float*)d_out, N);
}

// Round 2
// 592.492 us; speedup vs baseline: 1.2553x; 1.2553x over previous
//
#include <hip/hip_runtime.h>

// GraphSAGE encoder on MI355X.
// CSR build (atomic fill) -> mean-aggregate (1 wave/node) -> dense layers via
// split-bf16 MFMA (hi/lo decomposition gives fp32-equivalent accuracy:
// A@B ~= Ah@Bh + Al@Bh + Ah@Bl, dropped Al@Bl term ~2^-16 relative).

typedef unsigned short ushort_t;
typedef unsigned int uint_t;
typedef __attribute__((ext_vector_type(8))) short short8;
typedef __attribute__((ext_vector_type(4))) float f32x4;

// ---------------- bf16 helpers (manual RNE, no header dependence) ----------

__device__ inline ushort_t bf16_rne(float v) {
    uint_t u = __float_as_uint(v);
    u += 0x7fffu + ((u >> 16) & 1u);
    return (ushort_t)(u >> 16);
}
__device__ inline float bf16_to_f(ushort_t h) {
    return __uint_as_float((uint_t)h << 16);
}

// ---------------- CSR build ----------------

__global__ void k_count(const int* __restrict__ dst, int* __restrict__ deg, int E) {
    int e = blockIdx.x * blockDim.x + threadIdx.x;
    if (e < E) atomicAdd(&deg[dst[e]], 1);
}

__global__ void k_scan(const int* __restrict__ deg, int* __restrict__ off,
                       int* __restrict__ cur, int n) {
    __shared__ int s[1024];
    int tid = threadIdx.x;
    int chunk = (n + 1023) / 1024;
    int beg = tid * chunk;
    int end = beg + chunk; if (end > n) end = n;
    int sum = 0;
    for (int i = beg; i < end; ++i) sum += deg[i];
    s[tid] = sum;
    __syncthreads();
    for (int ofs = 1; ofs < 1024; ofs <<= 1) {
        int t = (tid >= ofs) ? s[tid - ofs] : 0;
        __syncthreads();
        s[tid] += t;
        __syncthreads();
    }
    int run = s[tid] - sum;
    for (int i = beg; i < end; ++i) {
        off[i] = run; cur[i] = run; run += deg[i];
    }
    if (tid == 1023) off[n] = s[1023];
}

__global__ void k_fill(const int* __restrict__ src, const int* __restrict__ dst,
                       int* __restrict__ cur, int* __restrict__ col, int E) {
    int e = blockIdx.x * blockDim.x + threadIdx.x;
    if (e < E) {
        int d = dst[e];
        int p = atomicAdd(&cur[d], 1);
        col[p] = src[e];
    }
}

// ---------------- input split / weight pack ----------------

// elementwise fp32 -> (hi, lo) bf16 pair
__global__ void k_split(const float* __restrict__ x, ushort_t* __restrict__ xh,
                        ushort_t* __restrict__ xl, int total) {
    int t = blockIdx.x * blockDim.x + threadIdx.x;
    if (t < total) {
        float v = x[t];
        ushort_t h = bf16_rne(v);
        xh[t] = h;
        xl[t] = bf16_rne(v - bf16_to_f(h));
    }
}

// Pack W (K x N, row-major fp32) into MFMA B-fragment order, hi then lo:
// dst[hl][kt][nt][lane][j], lane = (k/8 % 4)*16 + (n%16), j = k%8, kt=k/32, nt=n/16.
__global__ void k_pack_w(const float* __restrict__ W, ushort_t* __restrict__ dst,
                         int K, int N) {
    int t = blockIdx.x * blockDim.x + threadIdx.x;
    if (t >= K * N) return;
    int k = t / N, nn = t % N;
    int KT = K >> 5, NT = N >> 4;
    int kt = k >> 5, b = (k >> 3) & 3, j = k & 7;
    int nt = nn >> 4, lane = (b << 4) | (nn & 15);
    int base = (((kt * NT + nt) << 6) + lane) * 8 + j;
    int halfsz = KT * NT * 512;
    float v = W[t];
    ushort_t h = bf16_rne(v);
    dst[base] = h;
    dst[halfsz + base] = bf16_rne(v - bf16_to_f(h));
}

// ---------------- mean aggregation (one wave per node) ----------------

// layer 1: fp32 input (x, DIN=64), split-bf16 output
__global__ __launch_bounds__(256) void k_agg1(const float* __restrict__ feat,
                                              const int* __restrict__ off,
                                              const int* __restrict__ col,
                                              ushort_t* __restrict__ ah,
                                              ushort_t* __restrict__ al, int n) {
    int wave = (int)((blockIdx.x * (unsigned)blockDim.x + threadIdx.x) >> 6);
    int lane = threadIdx.x & 63;
    if (wave >= n) return;
    int s0 = off[wave], s1 = off[wave + 1];
    float a0 = 0.f;
    int e = s0;
    for (; e + 4 <= s1; e += 4) {
        int sA = col[e], sB = col[e + 1], sC = col[e + 2], sD = col[e + 3];
        a0 += feat[(size_t)sA * 64 + lane];
        a0 += feat[(size_t)sB * 64 + lane];
        a0 += feat[(size_t)sC * 64 + lane];
        a0 += feat[(size_t)sD * 64 + lane];
    }
    for (; e < s1; ++e) a0 += feat[(size_t)col[e] * 64 + lane];
    float m = a0 / fmaxf((float)(s1 - s0), 1.f);
    ushort_t h = bf16_rne(m);
    size_t idx = (size_t)wave * 64 + lane;
    ah[idx] = h;
    al[idx] = bf16_rne(m - bf16_to_f(h));
}

// layer 2: bf16-hi input (h1, DIN=128), split-bf16 output.
// Gathering hi only halves traffic; mean-of-rounded error ~6e-4 abs.
__global__ __launch_bounds__(256) void k_agg2(const ushort_t* __restrict__ fh,
                                              const int* __restrict__ off,
                                              const int* __restrict__ col,
                                              ushort_t* __restrict__ ah,
                                              ushort_t* __restrict__ al, int n) {
    int wave = (int)((blockIdx.x * (unsigned)blockDim.x + threadIdx.x) >> 6);
    int lane = threadIdx.x & 63;
    if (wave >= n) return;
    int s0 = off[wave], s1 = off[wave + 1];
    float a0 = 0.f, a1 = 0.f;
    int e = s0;
    for (; e + 4 <= s1; e += 4) {
        int sA = col[e], sB = col[e + 1], sC = col[e + 2], sD = col[e + 3];
        const ushort_t* rA = fh + (size_t)sA * 128;
        const ushort_t* rB = fh + (size_t)sB * 128;
        const ushort_t* rC = fh + (size_t)sC * 128;
        const ushort_t* rD = fh + (size_t)sD * 128;
        a0 += bf16_to_f(rA[lane]); a1 += bf16_to_f(rA[lane + 64]);
        a0 += bf16_to_f(rB[lane]); a1 += bf16_to_f(rB[lane + 64]);
        a0 += bf16_to_f(rC[lane]); a1 += bf16_to_f(rC[lane + 64]);
        a0 += bf16_to_f(rD[lane]); a1 += bf16_to_f(rD[lane + 64]);
    }
    for (; e < s1; ++e) {
        const ushort_t* r = fh + (size_t)col[e] * 128;
        a0 += bf16_to_f(r[lane]); a1 += bf16_to_f(r[lane + 64]);
    }
    float inv = 1.f / fmaxf((float)(s1 - s0), 1.f);
    float m0 = a0 * inv, m1 = a1 * inv;
    size_t idx = (size_t)wave * 128 + lane;
    ushort_t h0 = bf16_rne(m0), h1 = bf16_rne(m1);
    ah[idx] = h0;       al[idx] = bf16_rne(m0 - bf16_to_f(h0));
    ah[idx + 64] = h1;  al[idx + 64] = bf16_rne(m1 - bf16_to_f(h1));
}

// ---------------- MFMA dense ----------------
// One pass: acc += (Fh+Fl) @ (Wh+Wl) via 3 MFMA products.
// A-frag: A[m=lane&15][k=(lane>>4)*8+j] -> 16B contiguous loads from row-major bf16.
// B-frag: prepacked, lane-indexed 16B loads (L1/L2-hot).
// C/D: col=lane&15, row=(lane>>4)*4+reg.

template <int DIN, int DOUT, int M2>
__device__ inline void mfma_pass(const ushort_t* __restrict__ Fh,
                                 const ushort_t* __restrict__ Fl,
                                 const ushort_t* __restrict__ Wp,
                                 f32x4 (&acc)[M2][DOUT / 16],
                                 int base, int n, int lane) {
    constexpr int KT = DIN / 32, NT = DOUT / 16;
    int col = lane & 15, quad = lane >> 4;
    short8 fh[M2][KT], fl[M2][KT];
#pragma unroll
    for (int c = 0; c < M2; ++c) {
        int row = base + c * 16 + col;
        if (row >= n) row = n - 1;
        size_t roff = (size_t)row * DIN + quad * 8;
#pragma unroll
        for (int kt = 0; kt < KT; ++kt) {
            fh[c][kt] = *(const short8*)(Fh + roff + kt * 32);
            fl[c][kt] = *(const short8*)(Fl + roff + kt * 32);
        }
    }
#pragma unroll
    for (int nt = 0; nt < NT; ++nt) {
#pragma unroll
        for (int kt = 0; kt < KT; ++kt) {
            const ushort_t* p = Wp + ((size_t)((kt * NT + nt) << 6) + lane) * 8;
            short8 bh = *(const short8*)p;
            short8 bl = *(const short8*)(p + (size_t)KT * NT * 512);
#pragma unroll
            for (int c = 0; c < M2; ++c) {
                acc[c][nt] = __builtin_amdgcn_mfma_f32_16x16x32_bf16(fh[c][kt], bh, acc[c][nt], 0, 0, 0);
                acc[c][nt] = __builtin_amdgcn_mfma_f32_16x16x32_bf16(fl[c][kt], bh, acc[c][nt], 0, 0, 0);
                acc[c][nt] = __builtin_amdgcn_mfma_f32_16x16x32_bf16(fh[c][kt], bl, acc[c][nt], 0, 0, 0);
            }
        }
    }
}

template <int DIN, int DOUT, bool HAS_R, bool RELU, bool OUT_SPLIT>
__global__ __launch_bounds__(256)
void k_mfma_dense(const ushort_t* __restrict__ Ah, const ushort_t* __restrict__ Al,
                  const ushort_t* __restrict__ Xh, const ushort_t* __restrict__ Xl,
                  const ushort_t* __restrict__ Wlp, const ushort_t* __restrict__ Wrp,
                  const float* __restrict__ bias,
                  float* __restrict__ outF, ushort_t* __restrict__ Oh,
                  ushort_t* __restrict__ Ol, int n) {
    constexpr int NT = DOUT / 16, M2 = 2;
    int wave = (blockIdx.x * blockDim.x + threadIdx.x) >> 6;
    int lane = threadIdx.x & 63;
    int base = wave * (M2 * 16);
    if (base >= n) return;
    int col = lane & 15, quad = lane >> 4;

    f32x4 acc[M2][NT];
#pragma unroll
    for (int nt = 0; nt < NT; ++nt) {
        float bv = bias[nt * 16 + col];
#pragma unroll
        for (int c = 0; c < M2; ++c) acc[c][nt] = (f32x4){bv, bv, bv, bv};
    }

    mfma_pass<DIN, DOUT, M2>(Ah, Al, Wlp, acc, base, n, lane);
    if (HAS_R) mfma_pass<DIN, DOUT, M2>(Xh, Xl, Wrp, acc, base, n, lane);

#pragma unroll
    for (int c = 0; c < M2; ++c) {
        int rowb = base + c * 16 + quad * 4;
#pragma unroll
        for (int nt = 0; nt < NT; ++nt) {
            int cix = nt * 16 + col;
#pragma unroll
            for (int r = 0; r < 4; ++r) {
                int row = rowb + r;
                if (row < n) {
                    float v = acc[c][nt][r];
                    if (RELU) v = fmaxf(v, 0.f);
                    if (OUT_SPLIT) {
                        ushort_t h = bf16_rne(v);
                        Oh[(size_t)row * DOUT + cix] = h;
                        Ol[(size_t)row * DOUT + cix] = bf16_rne(v - bf16_to_f(h));
                    } else {
                        outF[(size_t)row * DOUT + cix] = v;
                    }
                }
            }
        }
    }
}

// ---------------- launch ----------------

static inline size_t align256(size_t x) { return (x + 255) & ~(size_t)255; }

extern "C" void kernel_launch(void* const* d_in, const int* in_sizes, int n_in,
                              void* d_out, int out_size, void* d_ws, size_t ws_size,
                              hipStream_t stream) {
    const float* x   = (const float*)d_in[0];
    const int*   ei  = (const int*)d_in[1];
    const float* Wl1 = (const float*)d_in[2];
    const float* bl1 = (const float*)d_in[3];
    const float* Wr1 = (const float*)d_in[4];
    const float* Wl2 = (const float*)d_in[5];
    const float* bl2 = (const float*)d_in[6];
    const float* Wr2 = (const float*)d_in[7];
    const float* Wo  = (const float*)d_in[8];
    const float* bo  = (const float*)d_in[9];

    const int N = in_sizes[0] / 64;   // 50000
    const int E = in_sizes[1] / 2;    // 1600000
    const int* src = ei;
    const int* dst = ei + E;

    // workspace carve
    char* ws = (char*)d_ws;
    int* deg = (int*)ws;            ws += align256((size_t)N * 4);
    int* off = (int*)ws;            ws += align256((size_t)(N + 1) * 4);
    int* cur = (int*)ws;            ws += align256((size_t)N * 4);
    int* col = (int*)ws;            ws += align256((size_t)E * 4);
    ushort_t* xh  = (ushort_t*)ws;  ws += align256((size_t)N * 64 * 2);
    ushort_t* xl  = (ushort_t*)ws;  ws += align256((size_t)N * 64 * 2);
    ushort_t* a1h = (ushort_t*)ws;  ws += align256((size_t)N * 64 * 2);
    ushort_t* a1l = (ushort_t*)ws;  ws += align256((size_t)N * 64 * 2);
    ushort_t* h1h = (ushort_t*)ws;  ws += align256((size_t)N * 128 * 2);
    ushort_t* h1l = (ushort_t*)ws;  ws += align256((size_t)N * 128 * 2);
    ushort_t* h2h = (ushort_t*)ws;  ws += align256((size_t)N * 128 * 2);
    ushort_t* h2l = (ushort_t*)ws;  ws += align256((size_t)N * 128 * 2);
    ushort_t* Wl1p = (ushort_t*)ws; ws += align256((size_t)2 * 64 * 128 * 2);
    ushort_t* Wr1p = (ushort_t*)ws; ws += align256((size_t)2 * 64 * 128 * 2);
    ushort_t* Wl2p = (ushort_t*)ws; ws += align256((size_t)2 * 128 * 128 * 2);
    ushort_t* Wr2p = (ushort_t*)ws; ws += align256((size_t)2 * 128 * 128 * 2);
    ushort_t* Wop  = (ushort_t*)ws; ws += align256((size_t)2 * 128 * 64 * 2);
    // a2 aliases the dead x/a1 split buffers (x,a1 consumed by dense1 before agg2)
    ushort_t* a2h = xh;   // 12.8 MB region (xh+xl)
    ushort_t* a2l = a1h;  // 12.8 MB region (a1h+a1l)

    // 1. CSR build
    hipMemsetAsync(deg, 0, (size_t)N * 4, stream);
    int ebl = (E + 255) / 256;
    k_count<<<ebl, 256, 0, stream>>>(dst, deg, E);
    k_scan<<<1, 1024, 0, stream>>>(deg, off, cur, N);
    k_fill<<<ebl, 256, 0, stream>>>(src, dst, cur, col, E);

    // 2. splits / weight packing (independent of CSR)
    k_split<<<(N * 64 + 255) / 256, 256, 0, stream>>>(x, xh, xl, N * 64);
    k_pack_w<<<(64 * 128 + 255) / 256, 256, 0, stream>>>(Wl1, Wl1p, 64, 128);
    k_pack_w<<<(64 * 128 + 255) / 256, 256, 0, stream>>>(Wr1, Wr1p, 64, 128);
    k_pack_w<<<(128 * 128 + 255) / 256, 256, 0, stream>>>(Wl2, Wl2p, 128, 128);
    k_pack_w<<<(128 * 128 + 255) / 256, 256, 0, stream>>>(Wr2, Wr2p, 128, 128);
    k_pack_w<<<(128 * 64 + 255) / 256, 256, 0, stream>>>(Wo, Wop, 128, 64);

    // 3. layer 1
    int aggbl = (N * 64 + 255) / 256;            // one wave per node
    k_agg1<<<aggbl, 256, 0, stream>>>(x, off, col, a1h, a1l, N);
    int dbl = ((N + 31) / 32 + 3) / 4;           // 32 nodes per wave, 4 waves/block
    k_mfma_dense<64, 128, true, true, true><<<dbl, 256, 0, stream>>>(
        a1h, a1l, xh, xl, Wl1p, Wr1p, bl1, nullptr, h1h, h1l, N);

    // 4. layer 2
    k_agg2<<<aggbl, 256, 0, stream>>>(h1h, off, col, a2h, a2l, N);
    k_mfma_dense<128, 128, true, true, true><<<dbl, 256, 0, stream>>>(
        a2h, a2l, h1h, h1l, Wl2p, Wr2p, bl2, nullptr, h2h, h2l, N);

    // 5. output layer
    k_mfma_dense<128, 64, false, false, false><<<dbl, 256, 0, stream>>>(
        h2h, h2l, nullptr, nullptr, Wop, nullptr, bo, (float*)d_out, nullptr, nullptr, N);
}

// Round 3
// 401.885 us; speedup vs baseline: 1.8507x; 1.4743x over previous
//
#include <hip/hip_runtime.h>

// GraphSAGE encoder on MI355X.
// CSR build via 2-level bucketing (no random HBM scatter) -> mean-aggregate
// (1 wave/node, bf16 gathers) -> dense layers via split-bf16 MFMA
// (A@B ~= Ah@Bh + Al@Bh + Ah@Bl, fp32-equivalent accuracy).

typedef unsigned short ushort_t;
typedef unsigned int uint_t;
typedef __attribute__((ext_vector_type(8))) short short8;
typedef __attribute__((ext_vector_type(4))) float f32x4;

#define BKT_SHIFT 7            // 128 nodes per bucket
#define BKT_NODES 128
#define BKT_CAP   5120         // mean 4096 + 16 sigma headroom
#define EPB       8192         // edges per block in bucket-scatter

// ---------------- bf16 helpers ----------------

__device__ inline ushort_t bf16_rne(float v) {
    uint_t u = __float_as_uint(v);
    u += 0x7fffu + ((u >> 16) & 1u);
    return (ushort_t)(u >> 16);
}
__device__ inline float bf16_to_f(ushort_t h) {
    return __uint_as_float((uint_t)h << 16);
}

// ---------------- CSR build, phase 1: bucket edges by dst>>7 ----------------
// Each block: LDS histogram over its EPB-edge chunk, reserve contiguous runs
// in each bucket via one atomicAdd per (block,bucket), then append. Global
// writes are ~64B contiguous runs at 391 bucket tails (L2-resident) -> write
// combining works, unlike the old 4B random scatter.

__global__ __launch_bounds__(256) void k_bucket(const int* __restrict__ src,
                                                const int* __restrict__ dst,
                                                uint_t* __restrict__ pairs,
                                                int* __restrict__ bcnt,
                                                int E, int nbk) {
    __shared__ int hist[512];
    __shared__ int base[512];
    int tid = threadIdx.x;
    int chunk = blockIdx.x * EPB;
    for (int i = tid; i < nbk; i += 256) hist[i] = 0;
    __syncthreads();
    for (int k = 0; k < EPB / 256; ++k) {
        int e = chunk + k * 256 + tid;
        if (e < E) atomicAdd(&hist[dst[e] >> BKT_SHIFT], 1);
    }
    __syncthreads();
    for (int i = tid; i < nbk; i += 256) {
        int c = hist[i];
        base[i] = c ? atomicAdd(&bcnt[i], c) : 0;
        hist[i] = 0;
    }
    __syncthreads();
    for (int k = 0; k < EPB / 256; ++k) {
        int e = chunk + k * 256 + tid;
        if (e < E) {
            int d = dst[e];
            int b = d >> BKT_SHIFT;
            int r = atomicAdd(&hist[b], 1);
            pairs[(size_t)b * BKT_CAP + base[b] + r] =
                (uint_t)(src[e] & 0xFFFF) | ((uint_t)(d & (BKT_NODES - 1)) << 16);
        }
    }
}

// phase 2a: per-bucket degree count (LDS atomics only), coalesced deg write
__global__ __launch_bounds__(256) void k_deg(const uint_t* __restrict__ pairs,
                                             const int* __restrict__ bcnt,
                                             int* __restrict__ deg, int n) {
    __shared__ int dl[BKT_NODES];
    int b = blockIdx.x, tid = threadIdx.x;
    if (tid < BKT_NODES) dl[tid] = 0;
    __syncthreads();
    int cnt = bcnt[b];
    const uint_t* p = pairs + (size_t)b * BKT_CAP;
    for (int i = tid; i < cnt; i += 256) atomicAdd(&dl[(p[i] >> 16) & 127], 1);
    __syncthreads();
    if (tid < BKT_NODES) {
        int node = b * BKT_NODES + tid;
        if (node < n) deg[node] = dl[tid];
    }
}

// single-block scan: deg -> off (exclusive, off[n]=E)
__global__ void k_scan(const int* __restrict__ deg, int* __restrict__ off, int n) {
    __shared__ int s[1024];
    int tid = threadIdx.x;
    int chunk = (n + 1023) / 1024;
    int beg = tid * chunk;
    int end = beg + chunk; if (end > n) end = n;
    int sum = 0;
    for (int i = beg; i < end; ++i) sum += deg[i];
    s[tid] = sum;
    __syncthreads();
    for (int ofs = 1; ofs < 1024; ofs <<= 1) {
        int t = (tid >= ofs) ? s[tid - ofs] : 0;
        __syncthreads();
        s[tid] += t;
        __syncthreads();
    }
    int run = s[tid] - sum;
    for (int i = beg; i < end; ++i) { off[i] = run; run += deg[i]; }
    if (tid == 1023) off[n] = s[1023];
}

// phase 2b: fine scatter. cur lives in LDS; col writes confined to the
// bucket's ~8KB window (L1/L2-resident -> write-combined).
__global__ __launch_bounds__(256) void k_fill2(const uint_t* __restrict__ pairs,
                                               const int* __restrict__ bcnt,
                                               const int* __restrict__ off,
                                               ushort_t* __restrict__ col, int n) {
    __shared__ int cur[BKT_NODES];
    int b = blockIdx.x, tid = threadIdx.x;
    if (tid < BKT_NODES) {
        int node = b * BKT_NODES + tid;
        cur[tid] = (node < n) ? off[node] : 0;
    }
    __syncthreads();
    int cnt = bcnt[b];
    const uint_t* p = pairs + (size_t)b * BKT_CAP;
    for (int i = tid; i < cnt; i += 256) {
        uint_t pk = p[i];
        int pos = atomicAdd(&cur[(pk >> 16) & 127], 1);
        col[pos] = (ushort_t)(pk & 0xFFFF);
    }
}

// ---------------- input split / weight pack ----------------

__global__ void k_split(const float* __restrict__ x, ushort_t* __restrict__ xh,
                        ushort_t* __restrict__ xl, int total) {
    int t = blockIdx.x * blockDim.x + threadIdx.x;
    if (t < total) {
        float v = x[t];
        ushort_t h = bf16_rne(v);
        xh[t] = h;
        xl[t] = bf16_rne(v - bf16_to_f(h));
    }
}

// Pack W (K x N row-major fp32) into MFMA B-fragment order, hi then lo.
__global__ void k_pack_w(const float* __restrict__ W, ushort_t* __restrict__ dst,
                         int K, int N) {
    int t = blockIdx.x * blockDim.x + threadIdx.x;
    if (t >= K * N) return;
    int k = t / N, nn = t % N;
    int KT = K >> 5, NT = N >> 4;
    int kt = k >> 5, b = (k >> 3) & 3, j = k & 7;
    int nt = nn >> 4, lane = (b << 4) | (nn & 15);
    int base = (((kt * NT + nt) << 6) + lane) * 8 + j;
    int halfsz = KT * NT * 512;
    float v = W[t];
    ushort_t h = bf16_rne(v);
    dst[base] = h;
    dst[halfsz + base] = bf16_rne(v - bf16_to_f(h));
}

// ---------------- mean aggregation (one wave per node, bf16-hi gathers) ----

template <int DIN>
__global__ __launch_bounds__(256) void k_agg(const ushort_t* __restrict__ fh,
                                             const int* __restrict__ off,
                                             const ushort_t* __restrict__ col,
                                             ushort_t* __restrict__ ah,
                                             ushort_t* __restrict__ al, int n) {
    int wave = (int)((blockIdx.x * (unsigned)blockDim.x + threadIdx.x) >> 6);
    int lane = threadIdx.x & 63;
    if (wave >= n) return;
    int s0 = off[wave], s1 = off[wave + 1];
    float a0 = 0.f, a1 = 0.f;
    int e = s0;
    for (; e + 4 <= s1; e += 4) {
        int sA = col[e], sB = col[e + 1], sC = col[e + 2], sD = col[e + 3];
        const ushort_t* rA = fh + (size_t)sA * DIN;
        const ushort_t* rB = fh + (size_t)sB * DIN;
        const ushort_t* rC = fh + (size_t)sC * DIN;
        const ushort_t* rD = fh + (size_t)sD * DIN;
        a0 += bf16_to_f(rA[lane]); a0 += bf16_to_f(rB[lane]);
        a0 += bf16_to_f(rC[lane]); a0 += bf16_to_f(rD[lane]);
        if (DIN == 128) {
            a1 += bf16_to_f(rA[lane + 64]); a1 += bf16_to_f(rB[lane + 64]);
            a1 += bf16_to_f(rC[lane + 64]); a1 += bf16_to_f(rD[lane + 64]);
        }
    }
    for (; e < s1; ++e) {
        const ushort_t* r = fh + (size_t)col[e] * DIN;
        a0 += bf16_to_f(r[lane]);
        if (DIN == 128) a1 += bf16_to_f(r[lane + 64]);
    }
    float inv = 1.f / fmaxf((float)(s1 - s0), 1.f);
    float m0 = a0 * inv;
    size_t idx = (size_t)wave * DIN + lane;
    ushort_t h0 = bf16_rne(m0);
    ah[idx] = h0; al[idx] = bf16_rne(m0 - bf16_to_f(h0));
    if (DIN == 128) {
        float m1 = a1 * inv;
        ushort_t h1 = bf16_rne(m1);
        ah[idx + 64] = h1; al[idx + 64] = bf16_rne(m1 - bf16_to_f(h1));
    }
}

// ---------------- MFMA dense ----------------
// acc += (Fh+Fl) @ (Wh+Wl) via 3 MFMA products per tile.
// A-frag: 16B contiguous loads from row-major bf16. B-frag: prepacked,
// lane-indexed 16B loads (L1/L2-hot). C/D: col=lane&15, row=(lane>>4)*4+reg.

template <int DIN, int DOUT, int M2>
__device__ inline void mfma_pass(const ushort_t* __restrict__ Fh,
                                 const ushort_t* __restrict__ Fl,
                                 const ushort_t* __restrict__ Wp,
                                 f32x4 (&acc)[M2][DOUT / 16],
                                 int base, int n, int lane) {
    constexpr int KT = DIN / 32, NT = DOUT / 16;
    int col = lane & 15, quad = lane >> 4;
    short8 fh[M2][KT], fl[M2][KT];
#pragma unroll
    for (int c = 0; c < M2; ++c) {
        int row = base + c * 16 + col;
        if (row >= n) row = n - 1;
        size_t roff = (size_t)row * DIN + quad * 8;
#pragma unroll
        for (int kt = 0; kt < KT; ++kt) {
            fh[c][kt] = *(const short8*)(Fh + roff + kt * 32);
            fl[c][kt] = *(const short8*)(Fl + roff + kt * 32);
        }
    }
#pragma unroll
    for (int nt = 0; nt < NT; ++nt) {
#pragma unroll
        for (int kt = 0; kt < KT; ++kt) {
            const ushort_t* p = Wp + ((size_t)((kt * NT + nt) << 6) + lane) * 8;
            short8 bh = *(const short8*)p;
            short8 bl = *(const short8*)(p + (size_t)KT * NT * 512);
#pragma unroll
            for (int c = 0; c < M2; ++c) {
                acc[c][nt] = __builtin_amdgcn_mfma_f32_16x16x32_bf16(fh[c][kt], bh, acc[c][nt], 0, 0, 0);
                acc[c][nt] = __builtin_amdgcn_mfma_f32_16x16x32_bf16(fl[c][kt], bh, acc[c][nt], 0, 0, 0);
                acc[c][nt] = __builtin_amdgcn_mfma_f32_16x16x32_bf16(fh[c][kt], bl, acc[c][nt], 0, 0, 0);
            }
        }
    }
}

template <int DIN, int DOUT, bool HAS_R, bool RELU, bool OUT_SPLIT>
__global__ __launch_bounds__(256)
void k_mfma_dense(const ushort_t* __restrict__ Ah, const ushort_t* __restrict__ Al,
                  const ushort_t* __restrict__ Xh, const ushort_t* __restrict__ Xl,
                  const ushort_t* __restrict__ Wlp, const ushort_t* __restrict__ Wrp,
                  const float* __restrict__ bias,
                  float* __restrict__ outF, ushort_t* __restrict__ Oh,
                  ushort_t* __restrict__ Ol, int n) {
    constexpr int NT = DOUT / 16, M2 = 2;
    int wave = (blockIdx.x * blockDim.x + threadIdx.x) >> 6;
    int lane = threadIdx.x & 63;
    int base = wave * (M2 * 16);
    if (base >= n) return;
    int col = lane & 15, quad = lane >> 4;

    f32x4 acc[M2][NT];
#pragma unroll
    for (int nt = 0; nt < NT; ++nt) {
        float bv = bias[nt * 16 + col];
#pragma unroll
        for (int c = 0; c < M2; ++c) acc[c][nt] = (f32x4){bv, bv, bv, bv};
    }

    mfma_pass<DIN, DOUT, M2>(Ah, Al, Wlp, acc, base, n, lane);
    if (HAS_R) mfma_pass<DIN, DOUT, M2>(Xh, Xl, Wrp, acc, base, n, lane);

#pragma unroll
    for (int c = 0; c < M2; ++c) {
        int rowb = base + c * 16 + quad * 4;
#pragma unroll
        for (int nt = 0; nt < NT; ++nt) {
            int cix = nt * 16 + col;
#pragma unroll
            for (int r = 0; r < 4; ++r) {
                int row = rowb + r;
                if (row < n) {
                    float v = acc[c][nt][r];
                    if (RELU) v = fmaxf(v, 0.f);
                    if (OUT_SPLIT) {
                        ushort_t h = bf16_rne(v);
                        Oh[(size_t)row * DOUT + cix] = h;
                        Ol[(size_t)row * DOUT + cix] = bf16_rne(v - bf16_to_f(h));
                    } else {
                        outF[(size_t)row * DOUT + cix] = v;
                    }
                }
            }
        }
    }
}

// ---------------- launch ----------------

static inline size_t align256(size_t x) { return (x + 255) & ~(size_t)255; }

extern "C" void kernel_launch(void* const* d_in, const int* in_sizes, int n_in,
                              void* d_out, int out_size, void* d_ws, size_t ws_size,
                              hipStream_t stream) {
    const float* x   = (const float*)d_in[0];
    const int*   ei  = (const int*)d_in[1];
    const float* Wl1 = (const float*)d_in[2];
    const float* bl1 = (const float*)d_in[3];
    const float* Wr1 = (const float*)d_in[4];
    const float* Wl2 = (const float*)d_in[5];
    const float* bl2 = (const float*)d_in[6];
    const float* Wr2 = (const float*)d_in[7];
    const float* Wo  = (const float*)d_in[8];
    const float* bo  = (const float*)d_in[9];

    const int N = in_sizes[0] / 64;   // 50000
    const int E = in_sizes[1] / 2;    // 1600000
    const int* src = ei;
    const int* dst = ei + E;
    const int nbk = (N + BKT_NODES - 1) >> BKT_SHIFT;   // 391 buckets

    // workspace carve
    char* ws = (char*)d_ws;
    int* deg = (int*)ws;            ws += align256((size_t)N * 4);
    int* off = (int*)ws;            ws += align256((size_t)(N + 1) * 4);
    int* bcnt = (int*)ws;           ws += align256((size_t)nbk * 4);
    uint_t* pairs = (uint_t*)ws;    ws += align256((size_t)nbk * BKT_CAP * 4);
    ushort_t* col = (ushort_t*)ws;  ws += align256((size_t)E * 2);
    ushort_t* xh  = (ushort_t*)ws;  ws += align256((size_t)N * 64 * 2);
    ushort_t* xl  = (ushort_t*)ws;  ws += align256((size_t)N * 64 * 2);
    ushort_t* a1h = (ushort_t*)ws;  ws += align256((size_t)N * 64 * 2);
    ushort_t* a1l = (ushort_t*)ws;  ws += align256((size_t)N * 64 * 2);
    ushort_t* h1h = (ushort_t*)ws;  ws += align256((size_t)N * 128 * 2);
    ushort_t* h1l = (ushort_t*)ws;  ws += align256((size_t)N * 128 * 2);
    ushort_t* h2h = (ushort_t*)ws;  ws += align256((size_t)N * 128 * 2);
    ushort_t* h2l = (ushort_t*)ws;  ws += align256((size_t)N * 128 * 2);
    ushort_t* Wl1p = (ushort_t*)ws; ws += align256((size_t)2 * 64 * 128 * 2);
    ushort_t* Wr1p = (ushort_t*)ws; ws += align256((size_t)2 * 64 * 128 * 2);
    ushort_t* Wl2p = (ushort_t*)ws; ws += align256((size_t)2 * 128 * 128 * 2);
    ushort_t* Wr2p = (ushort_t*)ws; ws += align256((size_t)2 * 128 * 128 * 2);
    ushort_t* Wop  = (ushort_t*)ws; ws += align256((size_t)2 * 128 * 64 * 2);
    // a2 aliases dead x/a1 split buffers (consumed by dense1 before agg2)
    ushort_t* a2h = xh;
    ushort_t* a2l = a1h;

    // 1. CSR build (bucketed, no random HBM scatter)
    hipMemsetAsync(bcnt, 0, (size_t)nbk * 4, stream);
    int bbl = (E + EPB - 1) / EPB;
    k_bucket<<<bbl, 256, 0, stream>>>(src, dst, pairs, bcnt, E, nbk);
    k_deg<<<nbk, 256, 0, stream>>>(pairs, bcnt, deg, N);
    k_scan<<<1, 1024, 0, stream>>>(deg, off, N);
    k_fill2<<<nbk, 256, 0, stream>>>(pairs, bcnt, off, col, N);

    // 2. splits / weight packing (independent of CSR)
    k_split<<<(N * 64 + 255) / 256, 256, 0, stream>>>(x, xh, xl, N * 64);
    k_pack_w<<<(64 * 128 + 255) / 256, 256, 0, stream>>>(Wl1, Wl1p, 64, 128);
    k_pack_w<<<(64 * 128 + 255) / 256, 256, 0, stream>>>(Wr1, Wr1p, 64, 128);
    k_pack_w<<<(128 * 128 + 255) / 256, 256, 0, stream>>>(Wl2, Wl2p, 128, 128);
    k_pack_w<<<(128 * 128 + 255) / 256, 256, 0, stream>>>(Wr2, Wr2p, 128, 128);
    k_pack_w<<<(128 * 64 + 255) / 256, 256, 0, stream>>>(Wo, Wop, 128, 64);

    // 3. layer 1 (agg gathers bf16-hi x)
    int aggbl = (N * 64 + 255) / 256;            // one wave per node
    k_agg<64><<<aggbl, 256, 0, stream>>>(xh, off, col, a1h, a1l, N);
    int dbl = ((N + 31) / 32 + 3) / 4;           // 32 nodes/wave, 4 waves/block
    k_mfma_dense<64, 128, true, true, true><<<dbl, 256, 0, stream>>>(
        a1h, a1l, xh, xl, Wl1p, Wr1p, bl1, nullptr, h1h, h1l, N);

    // 4. layer 2
    k_agg<128><<<aggbl, 256, 0, stream>>>(h1h, off, col, a2h, a2l, N);
    k_mfma_dense<128, 128, true, true, true><<<dbl, 256, 0, stream>>>(
        a2h, a2l, h1h, h1l, Wl2p, Wr2p, bl2, nullptr, h2h, h2l, N);

    // 5. output layer
    k_mfma_dense<128, 64, false, false, false><<<dbl, 256, 0, stream>>>(
        h2h, h2l, nullptr, nullptr, Wop, nullptr, bo, (float*)d_out, nullptr, nullptr, N);
}

// Round 4
// 290.367 us; speedup vs baseline: 2.5615x; 1.3841x over previous
//
#include <hip/hip_runtime.h>

// GraphSAGE encoder on MI355X.
// CSR build via 2-level bucketing (no random HBM scatter, no big serial scan)
// -> mean-aggregate (16B/lane multi-edge gathers) -> dense via split-bf16 MFMA
// (A@B ~= Ah@Bh + Al@Bh + Ah@Bl, fp32-equivalent accuracy).

typedef unsigned short ushort_t;
typedef unsigned int uint_t;
typedef __attribute__((ext_vector_type(8))) short short8;
typedef __attribute__((ext_vector_type(8))) ushort_t ushort8;
typedef __attribute__((ext_vector_type(4))) float f32x4;

#define BKT_SHIFT 7            // 128 nodes per bucket
#define BKT_NODES 128
#define BKT_CAP   5120         // mean 4092 + 16 sigma headroom
#define EPB       8192         // edges per block in bucket-scatter

// ---------------- bf16 helpers ----------------

__device__ inline ushort_t bf16_rne(float v) {
    uint_t u = __float_as_uint(v);
    u += 0x7fffu + ((u >> 16) & 1u);
    return (ushort_t)(u >> 16);
}
__device__ inline float bf16_to_f(ushort_t h) {
    return __uint_as_float((uint_t)h << 16);
}

// ---------------- CSR build ----------------
// phase 1: bucket edges by dst>>7. LDS histogram per chunk, reserve runs via
// one atomicAdd per (block,bucket), append packed (src | local<<16).

__global__ __launch_bounds__(256) void k_bucket(const int* __restrict__ src,
                                                const int* __restrict__ dst,
                                                uint_t* __restrict__ pairs,
                                                int* __restrict__ bcnt,
                                                int E, int nbk) {
    __shared__ int hist[512];
    __shared__ int base[512];
    int tid = threadIdx.x;
    int chunk = blockIdx.x * EPB;
    for (int i = tid; i < nbk; i += 256) hist[i] = 0;
    __syncthreads();
    for (int k = 0; k < EPB / 256; ++k) {
        int e = chunk + k * 256 + tid;
        if (e < E) atomicAdd(&hist[dst[e] >> BKT_SHIFT], 1);
    }
    __syncthreads();
    for (int i = tid; i < nbk; i += 256) {
        int c = hist[i];
        base[i] = c ? atomicAdd(&bcnt[i], c) : 0;
        hist[i] = 0;
    }
    __syncthreads();
    for (int k = 0; k < EPB / 256; ++k) {
        int e = chunk + k * 256 + tid;
        if (e < E) {
            int d = dst[e];
            int b = d >> BKT_SHIFT;
            int r = atomicAdd(&hist[b], 1);
            pairs[(size_t)b * BKT_CAP + base[b] + r] =
                (uint_t)(src[e] & 0xFFFF) | ((uint_t)(d & (BKT_NODES - 1)) << 16);
        }
    }
}

// phase 2: tiny single-block scan of 391 bucket counts -> bucket offsets
__global__ void k_bscan(const int* __restrict__ bcnt, int* __restrict__ boff,
                        int nbk) {
    __shared__ int s[512];
    int tid = threadIdx.x;
    int v = (tid < nbk) ? bcnt[tid] : 0;
    s[tid] = v;
    __syncthreads();
    for (int ofs = 1; ofs < 512; ofs <<= 1) {
        int t = (tid >= ofs) ? s[tid - ofs] : 0;
        __syncthreads();
        s[tid] += t;
        __syncthreads();
    }
    if (tid < nbk) boff[tid] = s[tid] - v;   // exclusive
}

// phase 3 (fused): per-bucket histogram + LDS scan + off write + fine scatter.
// pairs chunk (~16KB) is L1-resident across the two passes; col writes land in
// an ~8KB L2-resident window.
__global__ __launch_bounds__(256) void k_csr(const uint_t* __restrict__ pairs,
                                             const int* __restrict__ bcnt,
                                             const int* __restrict__ boff,
                                             int* __restrict__ off,
                                             ushort_t* __restrict__ col, int n) {
    __shared__ int hist[BKT_NODES];
    __shared__ int s[BKT_NODES];
    __shared__ int cur[BKT_NODES];
    int b = blockIdx.x, tid = threadIdx.x;
    if (tid < BKT_NODES) hist[tid] = 0;
    __syncthreads();
    int cnt = bcnt[b];
    const uint_t* p = pairs + (size_t)b * BKT_CAP;
    for (int i = tid; i < cnt; i += 256) atomicAdd(&hist[(p[i] >> 16) & 127], 1);
    __syncthreads();
    int v = (tid < BKT_NODES) ? hist[tid] : 0;
    if (tid < BKT_NODES) s[tid] = v;
    __syncthreads();
    for (int ofs = 1; ofs < BKT_NODES; ofs <<= 1) {
        int t = (tid >= ofs && tid < BKT_NODES) ? s[tid - ofs] : 0;
        __syncthreads();
        if (tid < BKT_NODES) s[tid] += t;
        __syncthreads();
    }
    if (tid < BKT_NODES) {
        int excl = boff[b] + s[tid] - v;
        int node = b * BKT_NODES + tid;
        if (node <= n) off[node] = excl;   // node==n gets E (all-zero tail degrees)
        cur[tid] = excl;
    }
    __syncthreads();
    for (int i = tid; i < cnt; i += 256) {
        uint_t pk = p[i];
        int pos = atomicAdd(&cur[(pk >> 16) & 127], 1);
        col[pos] = (ushort_t)(pk & 0xFFFF);
    }
}

// ---------------- input split / fused weight pack ----------------

__global__ void k_split(const float* __restrict__ x, ushort_t* __restrict__ xh,
                        ushort_t* __restrict__ xl, int total) {
    int t = blockIdx.x * blockDim.x + threadIdx.x;
    if (t < total) {
        float v = x[t];
        ushort_t h = bf16_rne(v);
        xh[t] = h;
        xl[t] = bf16_rne(v - bf16_to_f(h));
    }
}

struct WPack {
    const float* srcp[5];
    ushort_t* dstp[5];
    int K[5], N[5], beg[5], end[5];
};

// Pack W (K x N row-major fp32) into MFMA B-fragment order, hi then lo:
// dst[hl][kt][nt][lane][j], lane=(k/8%4)*16+(n%16), j=k%8.
__global__ void k_pack_all(WPack wp, int total) {
    int t = blockIdx.x * blockDim.x + threadIdx.x;
    if (t >= total) return;
#pragma unroll
    for (int m = 0; m < 5; ++m) {
        if (t >= wp.beg[m] && t < wp.end[m]) {
            int i = t - wp.beg[m];
            int K = wp.K[m], N = wp.N[m];
            int k = i / N, nn = i % N;
            int KT = K >> 5, NT = N >> 4;
            int kt = k >> 5, bq = (k >> 3) & 3, j = k & 7;
            int nt = nn >> 4, lane = (bq << 4) | (nn & 15);
            int base = (((kt * NT + nt) << 6) + lane) * 8 + j;
            int halfsz = KT * NT * 512;
            float v = wp.srcp[m][i];
            ushort_t h = bf16_rne(v);
            wp.dstp[m][base] = h;
            wp.dstp[m][halfsz + base] = bf16_rne(v - bf16_to_f(h));
        }
    }
}

// ---------------- mean aggregation ----------------
// One wave per node. 16B/lane packed-bf16 gathers: LPR = DIN/8 lanes cover one
// row, so EPI = 64/LPR edges load per instruction. Partial sums per lane-slice,
// shfl_xor butterfly across edge slots, 16B packed split-bf16 stores.

template <int DIN>
__global__ __launch_bounds__(256) void k_agg(const ushort_t* __restrict__ fh,
                                             const int* __restrict__ off,
                                             const ushort_t* __restrict__ col,
                                             ushort_t* __restrict__ ah,
                                             ushort_t* __restrict__ al, int n) {
    constexpr int LPR = DIN / 8;       // lanes per row: 8 (D64) / 16 (D128)
    constexpr int EPI = 64 / LPR;      // edges per instruction: 8 / 4
    int wave = (int)((blockIdx.x * (unsigned)blockDim.x + threadIdx.x) >> 6);
    int lane = threadIdx.x & 63;
    if (wave >= n) return;
    int li = lane & (LPR - 1);         // column slice
    int sub = lane / LPR;              // edge slot
    int s0 = off[wave], s1 = off[wave + 1];
    float a[8] = {0.f, 0.f, 0.f, 0.f, 0.f, 0.f, 0.f, 0.f};

    for (int e = s0; e < s1; e += 2 * EPI) {
        int i0 = e + sub, i1 = e + EPI + sub;
        float m0 = (i0 < s1) ? 1.f : 0.f;
        float m1 = (i1 < s1) ? 1.f : 0.f;
        int c0 = col[min(i0, s1 - 1)];
        int c1 = col[min(i1, s1 - 1)];
        uint4 q0 = *(const uint4*)(fh + (size_t)c0 * DIN + li * 8);
        uint4 q1 = *(const uint4*)(fh + (size_t)c1 * DIN + li * 8);
        const uint_t* u0 = (const uint_t*)&q0;
        const uint_t* u1 = (const uint_t*)&q1;
#pragma unroll
        for (int i = 0; i < 4; ++i) {
            a[2 * i]     = fmaf(m0, __uint_as_float(u0[i] << 16), a[2 * i]);
            a[2 * i + 1] = fmaf(m0, __uint_as_float(u0[i] & 0xffff0000u), a[2 * i + 1]);
        }
#pragma unroll
        for (int i = 0; i < 4; ++i) {
            a[2 * i]     = fmaf(m1, __uint_as_float(u1[i] << 16), a[2 * i]);
            a[2 * i + 1] = fmaf(m1, __uint_as_float(u1[i] & 0xffff0000u), a[2 * i + 1]);
        }
    }
    // combine edge slots
#pragma unroll
    for (int m = LPR; m < 64; m <<= 1) {
#pragma unroll
        for (int j = 0; j < 8; ++j) a[j] += __shfl_xor(a[j], m);
    }
    if (sub == 0) {
        float inv = 1.f / fmaxf((float)(s1 - s0), 1.f);
        ushort8 vh, vl;
#pragma unroll
        for (int j = 0; j < 8; ++j) {
            float m = a[j] * inv;
            ushort_t h = bf16_rne(m);
            vh[j] = h;
            vl[j] = bf16_rne(m - bf16_to_f(h));
        }
        *(ushort8*)(ah + (size_t)wave * DIN + li * 8) = vh;
        *(ushort8*)(al + (size_t)wave * DIN + li * 8) = vl;
    }
}

// ---------------- MFMA dense ----------------
// acc += (Fh+Fl) @ (Wh+Wl) via 3 MFMA products per tile.
// A-frag: 16B contiguous loads from row-major bf16. B-frag: prepacked,
// lane-indexed 16B loads (L1/L2-hot). C/D: col=lane&15, row=(lane>>4)*4+reg.

template <int DIN, int DOUT, int M2>
__device__ inline void mfma_pass(const ushort_t* __restrict__ Fh,
                                 const ushort_t* __restrict__ Fl,
                                 const ushort_t* __restrict__ Wp,
                                 f32x4 (&acc)[M2][DOUT / 16],
                                 int base, int n, int lane) {
    constexpr int KT = DIN / 32, NT = DOUT / 16;
    int col = lane & 15, quad = lane >> 4;
    short8 fh[M2][KT], fl[M2][KT];
#pragma unroll
    for (int c = 0; c < M2; ++c) {
        int row = base + c * 16 + col;
        if (row >= n) row = n - 1;
        size_t roff = (size_t)row * DIN + quad * 8;
#pragma unroll
        for (int kt = 0; kt < KT; ++kt) {
            fh[c][kt] = *(const short8*)(Fh + roff + kt * 32);
            fl[c][kt] = *(const short8*)(Fl + roff + kt * 32);
        }
    }
#pragma unroll
    for (int nt = 0; nt < NT; ++nt) {
#pragma unroll
        for (int kt = 0; kt < KT; ++kt) {
            const ushort_t* p = Wp + ((size_t)((kt * NT + nt) << 6) + lane) * 8;
            short8 bh = *(const short8*)p;
            short8 bl = *(const short8*)(p + (size_t)KT * NT * 512);
#pragma unroll
            for (int c = 0; c < M2; ++c) {
                acc[c][nt] = __builtin_amdgcn_mfma_f32_16x16x32_bf16(fh[c][kt], bh, acc[c][nt], 0, 0, 0);
                acc[c][nt] = __builtin_amdgcn_mfma_f32_16x16x32_bf16(fl[c][kt], bh, acc[c][nt], 0, 0, 0);
                acc[c][nt] = __builtin_amdgcn_mfma_f32_16x16x32_bf16(fh[c][kt], bl, acc[c][nt], 0, 0, 0);
            }
        }
    }
}

template <int DIN, int DOUT, bool HAS_R, bool RELU, bool OUT_SPLIT>
__global__ __launch_bounds__(256)
void k_mfma_dense(const ushort_t* __restrict__ Ah, const ushort_t* __restrict__ Al,
                  const ushort_t* __restrict__ Xh, const ushort_t* __restrict__ Xl,
                  const ushort_t* __restrict__ Wlp, const ushort_t* __restrict__ Wrp,
                  const float* __restrict__ bias,
                  float* __restrict__ outF, ushort_t* __restrict__ Oh,
                  ushort_t* __restrict__ Ol, int n) {
    constexpr int NT = DOUT / 16, M2 = 2;
    int wave = (blockIdx.x * blockDim.x + threadIdx.x) >> 6;
    int lane = threadIdx.x & 63;
    int base = wave * (M2 * 16);
    if (base >= n) return;
    int col = lane & 15, quad = lane >> 4;

    f32x4 acc[M2][NT];
#pragma unroll
    for (int nt = 0; nt < NT; ++nt) {
        float bv = bias[nt * 16 + col];
#pragma unroll
        for (int c = 0; c < M2; ++c) acc[c][nt] = (f32x4){bv, bv, bv, bv};
    }

    mfma_pass<DIN, DOUT, M2>(Ah, Al, Wlp, acc, base, n, lane);
    if (HAS_R) mfma_pass<DIN, DOUT, M2>(Xh, Xl, Wrp, acc, base, n, lane);

#pragma unroll
    for (int c = 0; c < M2; ++c) {
        int rowb = base + c * 16 + quad * 4;
#pragma unroll
        for (int nt = 0; nt < NT; ++nt) {
            int cix = nt * 16 + col;
#pragma unroll
            for (int r = 0; r < 4; ++r) {
                int row = rowb + r;
                if (row < n) {
                    float v = acc[c][nt][r];
                    if (RELU) v = fmaxf(v, 0.f);
                    if (OUT_SPLIT) {
                        ushort_t h = bf16_rne(v);
                        Oh[(size_t)row * DOUT + cix] = h;
                        Ol[(size_t)row * DOUT + cix] = bf16_rne(v - bf16_to_f(h));
                    } else {
                        outF[(size_t)row * DOUT + cix] = v;
                    }
                }
            }
        }
    }
}

// ---------------- launch ----------------

static inline size_t align256(size_t x) { return (x + 255) & ~(size_t)255; }

extern "C" void kernel_launch(void* const* d_in, const int* in_sizes, int n_in,
                              void* d_out, int out_size, void* d_ws, size_t ws_size,
                              hipStream_t stream) {
    const float* x   = (const float*)d_in[0];
    const int*   ei  = (const int*)d_in[1];
    const float* Wl1 = (const float*)d_in[2];
    const float* bl1 = (const float*)d_in[3];
    const float* Wr1 = (const float*)d_in[4];
    const float* Wl2 = (const float*)d_in[5];
    const float* bl2 = (const float*)d_in[6];
    const float* Wr2 = (const float*)d_in[7];
    const float* Wo  = (const float*)d_in[8];
    const float* bo  = (const float*)d_in[9];

    const int N = in_sizes[0] / 64;   // 50000
    const int E = in_sizes[1] / 2;    // 1600000
    const int* src = ei;
    const int* dst = ei + E;
    const int nbk = (N + BKT_NODES - 1) >> BKT_SHIFT;   // 391 buckets

    // workspace carve
    char* ws = (char*)d_ws;
    int* off = (int*)ws;            ws += align256((size_t)(N + 1) * 4);
    int* bcnt = (int*)ws;           ws += align256((size_t)nbk * 4);
    int* boff = (int*)ws;           ws += align256((size_t)nbk * 4);
    uint_t* pairs = (uint_t*)ws;    ws += align256((size_t)nbk * BKT_CAP * 4);
    ushort_t* col = (ushort_t*)ws;  ws += align256((size_t)E * 2);
    ushort_t* xh  = (ushort_t*)ws;  ws += align256((size_t)N * 64 * 2);
    ushort_t* xl  = (ushort_t*)ws;  ws += align256((size_t)N * 64 * 2);
    ushort_t* a1h = (ushort_t*)ws;  ws += align256((size_t)N * 64 * 2);
    ushort_t* a1l = (ushort_t*)ws;  ws += align256((size_t)N * 64 * 2);
    ushort_t* h1h = (ushort_t*)ws;  ws += align256((size_t)N * 128 * 2);
    ushort_t* h1l = (ushort_t*)ws;  ws += align256((size_t)N * 128 * 2);
    ushort_t* h2h = (ushort_t*)ws;  ws += align256((size_t)N * 128 * 2);
    ushort_t* h2l = (ushort_t*)ws;  ws += align256((size_t)N * 128 * 2);
    ushort_t* Wl1p = (ushort_t*)ws; ws += align256((size_t)2 * 64 * 128 * 2);
    ushort_t* Wr1p = (ushort_t*)ws; ws += align256((size_t)2 * 64 * 128 * 2);
    ushort_t* Wl2p = (ushort_t*)ws; ws += align256((size_t)2 * 128 * 128 * 2);
    ushort_t* Wr2p = (ushort_t*)ws; ws += align256((size_t)2 * 128 * 128 * 2);
    ushort_t* Wop  = (ushort_t*)ws; ws += align256((size_t)2 * 128 * 64 * 2);
    // a2 aliases dead x/a1 split buffers (consumed by dense1 before agg2)
    ushort_t* a2h = xh;
    ushort_t* a2l = a1h;

    // 1. CSR build (bucketed; no serial N-scan, no random HBM scatter)
    hipMemsetAsync(bcnt, 0, (size_t)nbk * 4, stream);
    int bbl = (E + EPB - 1) / EPB;
    k_bucket<<<bbl, 256, 0, stream>>>(src, dst, pairs, bcnt, E, nbk);
    k_bscan<<<1, 512, 0, stream>>>(bcnt, boff, nbk);
    k_csr<<<nbk, 256, 0, stream>>>(pairs, bcnt, boff, off, col, N);

    // 2. split + fused weight packing (independent of CSR)
    k_split<<<(N * 64 + 255) / 256, 256, 0, stream>>>(x, xh, xl, N * 64);
    WPack wp;
    wp.srcp[0] = Wl1; wp.dstp[0] = Wl1p; wp.K[0] = 64;  wp.N[0] = 128;
    wp.srcp[1] = Wr1; wp.dstp[1] = Wr1p; wp.K[1] = 64;  wp.N[1] = 128;
    wp.srcp[2] = Wl2; wp.dstp[2] = Wl2p; wp.K[2] = 128; wp.N[2] = 128;
    wp.srcp[3] = Wr2; wp.dstp[3] = Wr2p; wp.K[3] = 128; wp.N[3] = 128;
    wp.srcp[4] = Wo;  wp.dstp[4] = Wop;  wp.K[4] = 128; wp.N[4] = 64;
    int acc_el = 0;
    for (int m = 0; m < 5; ++m) {
        wp.beg[m] = acc_el; acc_el += wp.K[m] * wp.N[m]; wp.end[m] = acc_el;
    }
    k_pack_all<<<(acc_el + 255) / 256, 256, 0, stream>>>(wp, acc_el);

    // 3. layer 1 (agg gathers bf16-hi x)
    int aggbl = (N * 64 + 255) / 256;            // one wave per node
    k_agg<64><<<aggbl, 256, 0, stream>>>(xh, off, col, a1h, a1l, N);
    int dbl = ((N + 31) / 32 + 3) / 4;           // 32 nodes/wave, 4 waves/block
    k_mfma_dense<64, 128, true, true, true><<<dbl, 256, 0, stream>>>(
        a1h, a1l, xh, xl, Wl1p, Wr1p, bl1, nullptr, h1h, h1l, N);

    // 4. layer 2
    k_agg<128><<<aggbl, 256, 0, stream>>>(h1h, off, col, a2h, a2l, N);
    k_mfma_dense<128, 128, true, true, true><<<dbl, 256, 0, stream>>>(
        a2h, a2l, h1h, h1l, Wl2p, Wr2p, bl2, nullptr, h2h, h2l, N);

    // 5. output layer
    k_mfma_dense<128, 64, false, false, false><<<dbl, 256, 0, stream>>>(
        h2h, h2l, nullptr, nullptr, Wop, nullptr, bo, (float*)d_out, nullptr, nullptr, N);
}

// Round 5
// 269.672 us; speedup vs baseline: 2.7580x; 1.0767x over previous
//
#include <hip/hip_runtime.h>

// GraphSAGE encoder on MI355X.
// CSR build via 2-level bucketing (no random HBM scatter, no big serial scan)
// -> mean-aggregate (16B/lane, 4-deep-ILP gathers) -> dense via split-bf16 MFMA
// (A@B ~= Ah@Bh + Al@Bh + Ah@Bl, fp32-equivalent accuracy).

typedef unsigned short ushort_t;
typedef unsigned int uint_t;
typedef __attribute__((ext_vector_type(8))) short short8;
typedef __attribute__((ext_vector_type(8))) ushort_t ushort8;
typedef __attribute__((ext_vector_type(4))) float f32x4;

#define BKT_SHIFT 7            // 128 nodes per bucket
#define BKT_NODES 128
#define BKT_CAP   5120         // mean 4092 + 16 sigma headroom
#define EPB       8192         // edges per block in bucket-scatter

// ---------------- bf16 helpers ----------------

__device__ inline ushort_t bf16_rne(float v) {
    uint_t u = __float_as_uint(v);
    u += 0x7fffu + ((u >> 16) & 1u);
    return (ushort_t)(u >> 16);
}
__device__ inline float bf16_to_f(ushort_t h) {
    return __uint_as_float((uint_t)h << 16);
}

// ---------------- CSR build ----------------
// phase 1: bucket edges by dst>>7. LDS histogram per chunk, reserve runs via
// one atomicAdd per (block,bucket), append packed (src | local<<16).
// int4 edge loads: 16B/lane coalesced.

__global__ __launch_bounds__(256) void k_bucket(const int* __restrict__ src,
                                                const int* __restrict__ dst,
                                                uint_t* __restrict__ pairs,
                                                int* __restrict__ bcnt,
                                                int E, int nbk) {
    __shared__ int hist[512];
    __shared__ int base[512];
    int tid = threadIdx.x;
    int chunk = blockIdx.x * EPB;
    for (int i = tid; i < nbk; i += 256) hist[i] = 0;
    __syncthreads();
    for (int k = 0; k < EPB / 1024; ++k) {
        int e = chunk + (k * 256 + tid) * 4;
        if (e + 4 <= E) {
            int4 d4 = *(const int4*)(dst + e);
            atomicAdd(&hist[d4.x >> BKT_SHIFT], 1);
            atomicAdd(&hist[d4.y >> BKT_SHIFT], 1);
            atomicAdd(&hist[d4.z >> BKT_SHIFT], 1);
            atomicAdd(&hist[d4.w >> BKT_SHIFT], 1);
        } else {
            for (int t = e; t < E && t < e + 4; ++t)
                atomicAdd(&hist[dst[t] >> BKT_SHIFT], 1);
        }
    }
    __syncthreads();
    for (int i = tid; i < nbk; i += 256) {
        int c = hist[i];
        base[i] = c ? atomicAdd(&bcnt[i], c) : 0;
        hist[i] = 0;
    }
    __syncthreads();
    for (int k = 0; k < EPB / 1024; ++k) {
        int e = chunk + (k * 256 + tid) * 4;
        if (e + 4 <= E) {
            int4 d4 = *(const int4*)(dst + e);
            int4 s4 = *(const int4*)(src + e);
            int dd[4] = {d4.x, d4.y, d4.z, d4.w};
            int ss[4] = {s4.x, s4.y, s4.z, s4.w};
#pragma unroll
            for (int t = 0; t < 4; ++t) {
                int b = dd[t] >> BKT_SHIFT;
                int r = atomicAdd(&hist[b], 1);
                pairs[(size_t)b * BKT_CAP + base[b] + r] =
                    (uint_t)(ss[t] & 0xFFFF) | ((uint_t)(dd[t] & (BKT_NODES - 1)) << 16);
            }
        } else {
            for (int t = e; t < E && t < e + 4; ++t) {
                int d = dst[t];
                int b = d >> BKT_SHIFT;
                int r = atomicAdd(&hist[b], 1);
                pairs[(size_t)b * BKT_CAP + base[b] + r] =
                    (uint_t)(src[t] & 0xFFFF) | ((uint_t)(d & (BKT_NODES - 1)) << 16);
            }
        }
    }
}

// phase 2: tiny single-block scan of 391 bucket counts -> bucket offsets
__global__ void k_bscan(const int* __restrict__ bcnt, int* __restrict__ boff,
                        int nbk) {
    __shared__ int s[512];
    int tid = threadIdx.x;
    int v = (tid < nbk) ? bcnt[tid] : 0;
    s[tid] = v;
    __syncthreads();
    for (int ofs = 1; ofs < 512; ofs <<= 1) {
        int t = (tid >= ofs) ? s[tid - ofs] : 0;
        __syncthreads();
        s[tid] += t;
        __syncthreads();
    }
    if (tid < nbk) boff[tid] = s[tid] - v;   // exclusive
}

// phase 3 (fused): per-bucket histogram + LDS scan + off write + fine scatter.
__global__ __launch_bounds__(256) void k_csr(const uint_t* __restrict__ pairs,
                                             const int* __restrict__ bcnt,
                                             const int* __restrict__ boff,
                                             int* __restrict__ off,
                                             ushort_t* __restrict__ col, int n) {
    __shared__ int hist[BKT_NODES];
    __shared__ int s[BKT_NODES];
    __shared__ int cur[BKT_NODES];
    int b = blockIdx.x, tid = threadIdx.x;
    if (tid < BKT_NODES) hist[tid] = 0;
    __syncthreads();
    int cnt = bcnt[b];
    const uint_t* p = pairs + (size_t)b * BKT_CAP;
    for (int i = tid; i < cnt; i += 256) atomicAdd(&hist[(p[i] >> 16) & 127], 1);
    __syncthreads();
    int v = (tid < BKT_NODES) ? hist[tid] : 0;
    if (tid < BKT_NODES) s[tid] = v;
    __syncthreads();
    for (int ofs = 1; ofs < BKT_NODES; ofs <<= 1) {
        int t = (tid >= ofs && tid < BKT_NODES) ? s[tid - ofs] : 0;
        __syncthreads();
        if (tid < BKT_NODES) s[tid] += t;
        __syncthreads();
    }
    if (tid < BKT_NODES) {
        int excl = boff[b] + s[tid] - v;
        int node = b * BKT_NODES + tid;
        if (node <= n) off[node] = excl;   // node==n gets E (zero tail degrees)
        cur[tid] = excl;
    }
    __syncthreads();
    for (int i = tid; i < cnt; i += 256) {
        uint_t pk = p[i];
        int pos = atomicAdd(&cur[(pk >> 16) & 127], 1);
        col[pos] = (ushort_t)(pk & 0xFFFF);
    }
}

// ---------------- input split / fused weight pack ----------------

__global__ void k_split(const float* __restrict__ x, ushort_t* __restrict__ xh,
                        ushort_t* __restrict__ xl, int total) {
    int t = blockIdx.x * blockDim.x + threadIdx.x;
    if (t < total) {
        float v = x[t];
        ushort_t h = bf16_rne(v);
        xh[t] = h;
        xl[t] = bf16_rne(v - bf16_to_f(h));
    }
}

struct WPack {
    const float* srcp[5];
    ushort_t* dstp[5];
    int K[5], N[5], beg[5], end[5];
};

// Pack W (K x N row-major fp32) into MFMA B-fragment order, hi then lo:
// dst[hl][kt][nt][lane][j], lane=(k/8%4)*16+(n%16), j=k%8.
__global__ void k_pack_all(WPack wp, int total) {
    int t = blockIdx.x * blockDim.x + threadIdx.x;
    if (t >= total) return;
#pragma unroll
    for (int m = 0; m < 5; ++m) {
        if (t >= wp.beg[m] && t < wp.end[m]) {
            int i = t - wp.beg[m];
            int K = wp.K[m], N = wp.N[m];
            int k = i / N, nn = i % N;
            int KT = K >> 5, NT = N >> 4;
            int kt = k >> 5, bq = (k >> 3) & 3, j = k & 7;
            int nt = nn >> 4, lane = (bq << 4) | (nn & 15);
            int base = (((kt * NT + nt) << 6) + lane) * 8 + j;
            int halfsz = KT * NT * 512;
            float v = wp.srcp[m][i];
            ushort_t h = bf16_rne(v);
            wp.dstp[m][base] = h;
            wp.dstp[m][halfsz + base] = bf16_rne(v - bf16_to_f(h));
        }
    }
}

// ---------------- mean aggregation ----------------
// One wave per node. 16B/lane packed-bf16 gathers: LPR = DIN/8 lanes cover one
// row, EPI = 64/LPR edges per instruction. Full chunks: 4 gathers in flight,
// unmasked float2 adds (v_pk_add_f32). Masked 4-deep tail. shfl_xor butterfly.

__device__ inline void accum2(float2 (&a)[4], uint4 q) {
    const uint_t* u = (const uint_t*)&q;
#pragma unroll
    for (int i = 0; i < 4; ++i) {
        a[i].x += __uint_as_float(u[i] << 16);
        a[i].y += __uint_as_float(u[i] & 0xffff0000u);
    }
}
__device__ inline void accum2m(float2 (&a)[4], uint4 q, float m) {
    const uint_t* u = (const uint_t*)&q;
#pragma unroll
    for (int i = 0; i < 4; ++i) {
        a[i].x = fmaf(m, __uint_as_float(u[i] << 16), a[i].x);
        a[i].y = fmaf(m, __uint_as_float(u[i] & 0xffff0000u), a[i].y);
    }
}

template <int DIN>
__global__ __launch_bounds__(256) void k_agg(const ushort_t* __restrict__ fh,
                                             const int* __restrict__ off,
                                             const ushort_t* __restrict__ col,
                                             ushort_t* __restrict__ ah,
                                             ushort_t* __restrict__ al, int n) {
    constexpr int LPR = DIN / 8;       // lanes per row: 8 (D64) / 16 (D128)
    constexpr int EPI = 64 / LPR;      // edges per instruction: 8 / 4
    int wave = (int)((blockIdx.x * (unsigned)blockDim.x + threadIdx.x) >> 6);
    int lane = threadIdx.x & 63;
    if (wave >= n) return;
    int li = lane & (LPR - 1);         // column slice
    int sub = lane / LPR;              // edge slot
    int s0 = off[wave], s1 = off[wave + 1];
    float2 a2[4] = {{0.f, 0.f}, {0.f, 0.f}, {0.f, 0.f}, {0.f, 0.f}};
    const ushort_t* __restrict__ fbase = fh + li * 8;

    int e = s0;
    // full chunks: 4*EPI edges, 4 independent gathers, no masks
    for (; e + 4 * EPI <= s1; e += 4 * EPI) {
        int c0 = col[e + sub];
        int c1 = col[e + EPI + sub];
        int c2 = col[e + 2 * EPI + sub];
        int c3 = col[e + 3 * EPI + sub];
        uint4 q0 = *(const uint4*)(fbase + (size_t)c0 * DIN);
        uint4 q1 = *(const uint4*)(fbase + (size_t)c1 * DIN);
        uint4 q2 = *(const uint4*)(fbase + (size_t)c2 * DIN);
        uint4 q3 = *(const uint4*)(fbase + (size_t)c3 * DIN);
        accum2(a2, q0); accum2(a2, q1); accum2(a2, q2); accum2(a2, q3);
    }
    // masked tail (up to 4*EPI-1 edges), still 4 gathers in flight
    if (e < s1) {
        int last = s1 - 1;
        int i0 = e + sub, i1 = i0 + EPI, i2 = i1 + EPI, i3 = i2 + EPI;
        float m0 = (i0 < s1) ? 1.f : 0.f;
        float m1 = (i1 < s1) ? 1.f : 0.f;
        float m2 = (i2 < s1) ? 1.f : 0.f;
        float m3 = (i3 < s1) ? 1.f : 0.f;
        int c0 = col[min(i0, last)];
        int c1 = col[min(i1, last)];
        int c2 = col[min(i2, last)];
        int c3 = col[min(i3, last)];
        uint4 q0 = *(const uint4*)(fbase + (size_t)c0 * DIN);
        uint4 q1 = *(const uint4*)(fbase + (size_t)c1 * DIN);
        uint4 q2 = *(const uint4*)(fbase + (size_t)c2 * DIN);
        uint4 q3 = *(const uint4*)(fbase + (size_t)c3 * DIN);
        accum2m(a2, q0, m0); accum2m(a2, q1, m1);
        accum2m(a2, q2, m2); accum2m(a2, q3, m3);
    }
    // combine edge slots
#pragma unroll
    for (int m = LPR; m < 64; m <<= 1) {
#pragma unroll
        for (int j = 0; j < 4; ++j) {
            a2[j].x += __shfl_xor(a2[j].x, m);
            a2[j].y += __shfl_xor(a2[j].y, m);
        }
    }
    if (sub == 0) {
        float inv = 1.f / fmaxf((float)(s1 - s0), 1.f);
        ushort8 vh, vl;
#pragma unroll
        for (int j = 0; j < 4; ++j) {
            float mx = a2[j].x * inv;
            float my = a2[j].y * inv;
            ushort_t hx = bf16_rne(mx), hy = bf16_rne(my);
            vh[2 * j] = hx;     vl[2 * j] = bf16_rne(mx - bf16_to_f(hx));
            vh[2 * j + 1] = hy; vl[2 * j + 1] = bf16_rne(my - bf16_to_f(hy));
        }
        *(ushort8*)(ah + (size_t)wave * DIN + li * 8) = vh;
        *(ushort8*)(al + (size_t)wave * DIN + li * 8) = vl;
    }
}

// ---------------- MFMA dense ----------------
// acc += (Fh+Fl) @ (Wh+Wl) via 3 MFMA products per tile.
// A-frag: 16B contiguous loads from row-major bf16. B-frag: prepacked,
// lane-indexed 16B loads (L1/L2-hot). C/D: col=lane&15, row=(lane>>4)*4+reg.

template <int DIN, int DOUT, int M2>
__device__ inline void mfma_pass(const ushort_t* __restrict__ Fh,
                                 const ushort_t* __restrict__ Fl,
                                 const ushort_t* __restrict__ Wp,
                                 f32x4 (&acc)[M2][DOUT / 16],
                                 int base, int n, int lane) {
    constexpr int KT = DIN / 32, NT = DOUT / 16;
    int col = lane & 15, quad = lane >> 4;
    short8 fh[M2][KT], fl[M2][KT];
#pragma unroll
    for (int c = 0; c < M2; ++c) {
        int row = base + c * 16 + col;
        if (row >= n) row = n - 1;
        size_t roff = (size_t)row * DIN + quad * 8;
#pragma unroll
        for (int kt = 0; kt < KT; ++kt) {
            fh[c][kt] = *(const short8*)(Fh + roff + kt * 32);
            fl[c][kt] = *(const short8*)(Fl + roff + kt * 32);
        }
    }
#pragma unroll
    for (int nt = 0; nt < NT; ++nt) {
#pragma unroll
        for (int kt = 0; kt < KT; ++kt) {
            const ushort_t* p = Wp + ((size_t)((kt * NT + nt) << 6) + lane) * 8;
            short8 bh = *(const short8*)p;
            short8 bl = *(const short8*)(p + (size_t)KT * NT * 512);
#pragma unroll
            for (int c = 0; c < M2; ++c) {
                acc[c][nt] = __builtin_amdgcn_mfma_f32_16x16x32_bf16(fh[c][kt], bh, acc[c][nt], 0, 0, 0);
                acc[c][nt] = __builtin_amdgcn_mfma_f32_16x16x32_bf16(fl[c][kt], bh, acc[c][nt], 0, 0, 0);
                acc[c][nt] = __builtin_amdgcn_mfma_f32_16x16x32_bf16(fh[c][kt], bl, acc[c][nt], 0, 0, 0);
            }
        }
    }
}

template <int DIN, int DOUT, bool HAS_R, bool RELU, bool OUT_SPLIT>
__global__ __launch_bounds__(256)
void k_mfma_dense(const ushort_t* __restrict__ Ah, const ushort_t* __restrict__ Al,
                  const ushort_t* __restrict__ Xh, const ushort_t* __restrict__ Xl,
                  const ushort_t* __restrict__ Wlp, const ushort_t* __restrict__ Wrp,
                  const float* __restrict__ bias,
                  float* __restrict__ outF, ushort_t* __restrict__ Oh,
                  ushort_t* __restrict__ Ol, int n) {
    constexpr int NT = DOUT / 16, M2 = 2;
    int wave = (blockIdx.x * blockDim.x + threadIdx.x) >> 6;
    int lane = threadIdx.x & 63;
    int base = wave * (M2 * 16);
    if (base >= n) return;
    int col = lane & 15, quad = lane >> 4;

    f32x4 acc[M2][NT];
#pragma unroll
    for (int nt = 0; nt < NT; ++nt) {
        float bv = bias[nt * 16 + col];
#pragma unroll
        for (int c = 0; c < M2; ++c) acc[c][nt] = (f32x4){bv, bv, bv, bv};
    }

    mfma_pass<DIN, DOUT, M2>(Ah, Al, Wlp, acc, base, n, lane);
    if (HAS_R) mfma_pass<DIN, DOUT, M2>(Xh, Xl, Wrp, acc, base, n, lane);

#pragma unroll
    for (int c = 0; c < M2; ++c) {
        int rowb = base + c * 16 + quad * 4;
#pragma unroll
        for (int nt = 0; nt < NT; ++nt) {
            int cix = nt * 16 + col;
#pragma unroll
            for (int r = 0; r < 4; ++r) {
                int row = rowb + r;
                if (row < n) {
                    float v = acc[c][nt][r];
                    if (RELU) v = fmaxf(v, 0.f);
                    if (OUT_SPLIT) {
                        ushort_t h = bf16_rne(v);
                        Oh[(size_t)row * DOUT + cix] = h;
                        Ol[(size_t)row * DOUT + cix] = bf16_rne(v - bf16_to_f(h));
                    } else {
                        outF[(size_t)row * DOUT + cix] = v;
                    }
                }
            }
        }
    }
}

// ---------------- launch ----------------

static inline size_t align256(size_t x) { return (x + 255) & ~(size_t)255; }

extern "C" void kernel_launch(void* const* d_in, const int* in_sizes, int n_in,
                              void* d_out, int out_size, void* d_ws, size_t ws_size,
                              hipStream_t stream) {
    const float* x   = (const float*)d_in[0];
    const int*   ei  = (const int*)d_in[1];
    const float* Wl1 = (const float*)d_in[2];
    const float* bl1 = (const float*)d_in[3];
    const float* Wr1 = (const float*)d_in[4];
    const float* Wl2 = (const float*)d_in[5];
    const float* bl2 = (const float*)d_in[6];
    const float* Wr2 = (const float*)d_in[7];
    const float* Wo  = (const float*)d_in[8];
    const float* bo  = (const float*)d_in[9];

    const int N = in_sizes[0] / 64;   // 50000
    const int E = in_sizes[1] / 2;    // 1600000
    const int* src = ei;
    const int* dst = ei + E;
    const int nbk = (N + BKT_NODES - 1) >> BKT_SHIFT;   // 391 buckets

    // workspace carve
    char* ws = (char*)d_ws;
    int* off = (int*)ws;            ws += align256((size_t)(N + 1) * 4);
    int* bcnt = (int*)ws;           ws += align256((size_t)nbk * 4);
    int* boff = (int*)ws;           ws += align256((size_t)nbk * 4);
    uint_t* pairs = (uint_t*)ws;    ws += align256((size_t)nbk * BKT_CAP * 4);
    ushort_t* col = (ushort_t*)ws;  ws += align256((size_t)E * 2);
    ushort_t* xh  = (ushort_t*)ws;  ws += align256((size_t)N * 64 * 2);
    ushort_t* xl  = (ushort_t*)ws;  ws += align256((size_t)N * 64 * 2);
    ushort_t* a1h = (ushort_t*)ws;  ws += align256((size_t)N * 64 * 2);
    ushort_t* a1l = (ushort_t*)ws;  ws += align256((size_t)N * 64 * 2);
    ushort_t* h1h = (ushort_t*)ws;  ws += align256((size_t)N * 128 * 2);
    ushort_t* h1l = (ushort_t*)ws;  ws += align256((size_t)N * 128 * 2);
    ushort_t* h2h = (ushort_t*)ws;  ws += align256((size_t)N * 128 * 2);
    ushort_t* h2l = (ushort_t*)ws;  ws += align256((size_t)N * 128 * 2);
    ushort_t* Wl1p = (ushort_t*)ws; ws += align256((size_t)2 * 64 * 128 * 2);
    ushort_t* Wr1p = (ushort_t*)ws; ws += align256((size_t)2 * 64 * 128 * 2);
    ushort_t* Wl2p = (ushort_t*)ws; ws += align256((size_t)2 * 128 * 128 * 2);
    ushort_t* Wr2p = (ushort_t*)ws; ws += align256((size_t)2 * 128 * 128 * 2);
    ushort_t* Wop  = (ushort_t*)ws; ws += align256((size_t)2 * 128 * 64 * 2);
    // a2 aliases dead x/a1 split buffers (consumed by dense1 before agg2)
    ushort_t* a2h = xh;
    ushort_t* a2l = a1h;

    // 1. CSR build (bucketed; no serial N-scan, no random HBM scatter)
    hipMemsetAsync(bcnt, 0, (size_t)nbk * 4, stream);
    int bbl = (E + EPB - 1) / EPB;
    k_bucket<<<bbl, 256, 0, stream>>>(src, dst, pairs, bcnt, E, nbk);
    k_bscan<<<1, 512, 0, stream>>>(bcnt, boff, nbk);
    k_csr<<<nbk, 256, 0, stream>>>(pairs, bcnt, boff, off, col, N);

    // 2. split + fused weight packing (independent of CSR)
    k_split<<<(N * 64 + 255) / 256, 256, 0, stream>>>(x, xh, xl, N * 64);
    WPack wp;
    wp.srcp[0] = Wl1; wp.dstp[0] = Wl1p; wp.K[0] = 64;  wp.N[0] = 128;
    wp.srcp[1] = Wr1; wp.dstp[1] = Wr1p; wp.K[1] = 64;  wp.N[1] = 128;
    wp.srcp[2] = Wl2; wp.dstp[2] = Wl2p; wp.K[2] = 128; wp.N[2] = 128;
    wp.srcp[3] = Wr2; wp.dstp[3] = Wr2p; wp.K[3] = 128; wp.N[3] = 128;
    wp.srcp[4] = Wo;  wp.dstp[4] = Wop;  wp.K[4] = 128; wp.N[4] = 64;
    int acc_el = 0;
    for (int m = 0; m < 5; ++m) {
        wp.beg[m] = acc_el; acc_el += wp.K[m] * wp.N[m]; wp.end[m] = acc_el;
    }
    k_pack_all<<<(acc_el + 255) / 256, 256, 0, stream>>>(wp, acc_el);

    // 3. layer 1 (agg gathers bf16-hi x)
    int aggbl = (N * 64 + 255) / 256;            // one wave per node
    k_agg<64><<<aggbl, 256, 0, stream>>>(xh, off, col, a1h, a1l, N);
    int dbl = ((N + 31) / 32 + 3) / 4;           // 32 nodes/wave, 4 waves/block
    k_mfma_dense<64, 128, true, true, true><<<dbl, 256, 0, stream>>>(
        a1h, a1l, xh, xl, Wl1p, Wr1p, bl1, nullptr, h1h, h1l, N);

    // 4. layer 2
    k_agg<128><<<aggbl, 256, 0, stream>>>(h1h, off, col, a2h, a2l, N);
    k_mfma_dense<128, 128, true, true, true><<<dbl, 256, 0, stream>>>(
        a2h, a2l, h1h, h1l, Wl2p, Wr2p, bl2, nullptr, h2h, h2l, N);

    // 5. output layer
    k_mfma_dense<128, 64, false, false, false><<<dbl, 256, 0, stream>>>(
        h2h, h2l, nullptr, nullptr, Wop, nullptr, bo, (float*)d_out, nullptr, nullptr, N);
}